// Round 1
// baseline (92.921 us; speedup 1.0000x reference)
//
#include <hip/hip_runtime.h>

// TripleGrainSeparatePermuter: per-row stable 3-way stream compaction.
// B=512 rows, N=4096 elements/row. 9 outputs of [B, N+1]=[512,4097] int32,
// concatenated flat in d_out in reference return order:
//   0: coarse_content  1: medium_content  2: fine_content
//   3: coarse_position 4: medium_position 5: fine_position
//   6: coarse_segment  7: medium_segment  8: fine_segment

constexpr int N_TOK  = 4096;
constexpr int M_OUT  = N_TOK + 1;   // 4097
constexpr int TPB    = 256;
constexpr int EPT    = N_TOK / TPB; // 16 elements per thread (contiguous chunk)

constexpr int CONTENT_PAD = 1024, CONTENT_EOS = 1025;
// per-class position pad/eos: coarse 128/129, medium 256/257, fine 1024/1025
__device__ __constant__ int POS_PAD[3] = {128, 256, 1024};
__device__ __constant__ int POS_EOS[3] = {129, 257, 1025};

__global__ __launch_bounds__(TPB) void
triple_grain_permute(const int* __restrict__ indices,
                     const int* __restrict__ grain,
                     int* __restrict__ out,
                     int batch) {
    const int b = blockIdx.x;
    const int t = threadIdx.x;
    const int lane = t & 63;
    const int wave = t >> 6;

    const int* idx_row = indices + (size_t)b * N_TOK;
    const int* g_row   = grain   + (size_t)b * N_TOK;

    __shared__ int s_content[N_TOK];
    __shared__ int s_pos[N_TOK];
    __shared__ unsigned long long s_wave_tot[4];

    // ---- load my contiguous 16-element chunk (4 x int4, 64B-aligned) ----
    int gv[EPT], iv[EPT];
    {
        const int4* g4 = reinterpret_cast<const int4*>(g_row + t * EPT);
        const int4* i4 = reinterpret_cast<const int4*>(idx_row + t * EPT);
#pragma unroll
        for (int k = 0; k < EPT / 4; ++k) {
            int4 gg = g4[k];
            int4 ii = i4[k];
            gv[4 * k + 0] = gg.x; gv[4 * k + 1] = gg.y;
            gv[4 * k + 2] = gg.z; gv[4 * k + 3] = gg.w;
            iv[4 * k + 0] = ii.x; iv[4 * k + 1] = ii.y;
            iv[4 * k + 2] = ii.z; iv[4 * k + 3] = ii.w;
        }
    }

    // ---- per-thread class counts, packed into 21-bit fields ----
    int c0 = 0, c1 = 0, c2 = 0;
#pragma unroll
    for (int j = 0; j < EPT; ++j) {
        c0 += (gv[j] == 0);
        c1 += (gv[j] == 1);
        c2 += (gv[j] == 2);
    }
    unsigned long long packed =
        (unsigned long long)c0 |
        ((unsigned long long)c1 << 21) |
        ((unsigned long long)c2 << 42);

    // ---- wave-64 inclusive scan (single packed scan does all 3 classes) ----
    unsigned long long inc = packed;
#pragma unroll
    for (int off = 1; off < 64; off <<= 1) {
        unsigned long long nb =
            (unsigned long long)__shfl_up((long long)inc, off, 64);
        if (lane >= off) inc += nb;
    }
    if (lane == 63) s_wave_tot[wave] = inc;
    __syncthreads();

    unsigned long long wave_prefix = 0, total = 0;
#pragma unroll
    for (int w = 0; w < 4; ++w) {
        unsigned long long v = s_wave_tot[w];
        if (w < wave) wave_prefix += v;
        total += v;
    }
    const unsigned long long excl = wave_prefix + (inc - packed);

    const int o0 = (int)(excl & 0x1FFFFF);
    const int o1 = (int)((excl >> 21) & 0x1FFFFF);
    const int o2 = (int)((excl >> 42) & 0x1FFFFF);
    const int cnt0 = (int)(total & 0x1FFFFF);
    const int cnt1 = (int)((total >> 21) & 0x1FFFFF);
    const int cnt2 = (int)((total >> 42) & 0x1FFFFF);

    // compacted class segments laid back-to-back in LDS
    const int base0 = 0, base1 = cnt0, base2 = cnt0 + cnt1;

    // ---- scatter my chunk into LDS (stable: chunk is contiguous, scan ordered) ----
    int d0 = base0 + o0, d1 = base1 + o1, d2 = base2 + o2;
    const int elem0 = t * EPT;
#pragma unroll
    for (int j = 0; j < EPT; ++j) {
        const int c = gv[j];
        const int dst = (c == 0) ? d0 : ((c == 1) ? d1 : d2);
        s_content[dst] = iv[j];
        s_pos[dst]     = elem0 + j;
        d0 += (c == 0);
        d1 += (c == 1);
        d2 += (c == 2);
    }
    __syncthreads();

    // ---- coalesced write-out: per class, content + position + segment ----
    const size_t ARR = (size_t)batch * M_OUT;   // elements per output array
    const int bases[3] = {base0, base1, base2};
    const int cnts[3]  = {cnt0, cnt1, cnt2};

#pragma unroll
    for (int c = 0; c < 3; ++c) {
        int* dst_c = out + (size_t)c       * ARR + (size_t)b * M_OUT;
        int* dst_p = out + (size_t)(3 + c) * ARR + (size_t)b * M_OUT;
        int* dst_s = out + (size_t)(6 + c) * ARR + (size_t)b * M_OUT;
        const int cnt = cnts[c];
        const int base = bases[c];
        const int peos = POS_EOS[c], ppad = POS_PAD[c];
        for (int slot = t; slot < M_OUT; slot += TPB) {
            int vc, vp;
            if (slot < cnt) {
                vc = s_content[base + slot];
                vp = s_pos[base + slot];
            } else if (slot == cnt) {
                vc = CONTENT_EOS;
                vp = peos;
            } else {
                vc = CONTENT_PAD;
                vp = ppad;
            }
            dst_c[slot] = vc;
            dst_p[slot] = vp;
            dst_s[slot] = c;
        }
    }
}

extern "C" void kernel_launch(void* const* d_in, const int* in_sizes, int n_in,
                              void* d_out, int out_size, void* d_ws, size_t ws_size,
                              hipStream_t stream) {
    const int* indices = (const int*)d_in[0];
    const int* grain   = (const int*)d_in[1];
    int* out = (int*)d_out;

    const int batch = in_sizes[0] / N_TOK;  // 512
    triple_grain_permute<<<batch, TPB, 0, stream>>>(indices, grain, out, batch);
}

// Round 2
// 91.002 us; speedup vs baseline: 1.0211x; 1.0211x over previous
//
#include <hip/hip_runtime.h>

// TripleGrainSeparatePermuter: per-row stable 3-way stream compaction.
// B=512 rows, N=4096 elements/row. 9 outputs of [B, N+1]=[512,4097] int32,
// concatenated flat in d_out in reference return order:
//   0: coarse_content  1: medium_content  2: fine_content
//   3: coarse_position 4: medium_position 5: fine_position
//   6: coarse_segment  7: medium_segment  8: fine_segment

constexpr int N_TOK  = 4096;
constexpr int M_OUT  = N_TOK + 1;   // 4097
constexpr int TPB    = 1024;        // 16 waves/block, 2 blocks/CU -> 32 waves/CU (max)
constexpr int NWAVES = TPB / 64;
constexpr int EPT    = N_TOK / TPB; // 4 elements per thread (contiguous chunk)

constexpr int CONTENT_PAD = 1024, CONTENT_EOS = 1025;
// per-class position pad/eos: coarse 128/129, medium 256/257, fine 1024/1025
__device__ __constant__ int POS_PAD[3] = {128, 256, 1024};
__device__ __constant__ int POS_EOS[3] = {129, 257, 1025};

__global__ __launch_bounds__(TPB, 8) void
triple_grain_permute(const int* __restrict__ indices,
                     const int* __restrict__ grain,
                     int* __restrict__ out,
                     int batch) {
    const int b = blockIdx.x;
    const int t = threadIdx.x;
    const int lane = t & 63;
    const int wave = t >> 6;

    const int* idx_row = indices + (size_t)b * N_TOK;
    const int* g_row   = grain   + (size_t)b * N_TOK;

    // packed per-token word: content (bits 0..11, values<=1023) | pos<<12 (<=4095)
    __shared__ int s_packed[N_TOK];
    __shared__ unsigned long long s_wave_tot[NWAVES];

    // ---- load my contiguous 4-element chunk (int4, 16B-aligned) ----
    int4 gg = reinterpret_cast<const int4*>(g_row)[t];
    int4 ii = reinterpret_cast<const int4*>(idx_row)[t];
    int gv[EPT] = {gg.x, gg.y, gg.z, gg.w};
    const int elem0 = t * EPT;
    int pv[EPT] = {ii.x | (elem0 << 12),
                   ii.y | ((elem0 + 1) << 12),
                   ii.z | ((elem0 + 2) << 12),
                   ii.w | ((elem0 + 3) << 12)};

    // ---- per-thread class counts, packed into 21-bit fields ----
    int c0 = 0, c1 = 0, c2 = 0;
#pragma unroll
    for (int j = 0; j < EPT; ++j) {
        c0 += (gv[j] == 0);
        c1 += (gv[j] == 1);
        c2 += (gv[j] == 2);
    }
    unsigned long long packed =
        (unsigned long long)c0 |
        ((unsigned long long)c1 << 21) |
        ((unsigned long long)c2 << 42);

    // ---- wave-64 inclusive scan (single packed scan covers all 3 classes) ----
    unsigned long long inc = packed;
#pragma unroll
    for (int off = 1; off < 64; off <<= 1) {
        unsigned long long nb =
            (unsigned long long)__shfl_up((long long)inc, off, 64);
        if (lane >= off) inc += nb;
    }
    if (lane == 63) s_wave_tot[wave] = inc;
    __syncthreads();

    unsigned long long wave_prefix = 0, total = 0;
#pragma unroll
    for (int w = 0; w < NWAVES; ++w) {
        unsigned long long v = s_wave_tot[w];
        if (w < wave) wave_prefix += v;
        total += v;
    }
    const unsigned long long excl = wave_prefix + (inc - packed);

    const int o0 = (int)(excl & 0x1FFFFF);
    const int o1 = (int)((excl >> 21) & 0x1FFFFF);
    const int o2 = (int)((excl >> 42) & 0x1FFFFF);
    const int cnt0 = (int)(total & 0x1FFFFF);
    const int cnt1 = (int)((total >> 21) & 0x1FFFFF);
    const int cnt2 = (int)((total >> 42) & 0x1FFFFF);

    // compacted class segments laid back-to-back in LDS
    const int base0 = 0, base1 = cnt0, base2 = cnt0 + cnt1;

    // ---- scatter my chunk into LDS (stable: contiguous chunk, ordered scan) ----
    int d0 = base0 + o0, d1 = base1 + o1, d2 = base2 + o2;
#pragma unroll
    for (int j = 0; j < EPT; ++j) {
        const int c = gv[j];
        const int dst = (c == 0) ? d0 : ((c == 1) ? d1 : d2);
        s_packed[dst] = pv[j];
        d0 += (c == 0);
        d1 += (c == 1);
        d2 += (c == 2);
    }
    __syncthreads();

    // ---- coalesced write-out: per class, content + position + segment ----
    const size_t ARR = (size_t)batch * M_OUT;   // elements per output array
    const int bases[3] = {base0, base1, base2};
    const int cnts[3]  = {cnt0, cnt1, cnt2};

#pragma unroll
    for (int c = 0; c < 3; ++c) {
        int* dst_c = out + (size_t)c       * ARR + (size_t)b * M_OUT;
        int* dst_p = out + (size_t)(3 + c) * ARR + (size_t)b * M_OUT;
        int* dst_s = out + (size_t)(6 + c) * ARR + (size_t)b * M_OUT;
        const int cnt = cnts[c];
        const int base = bases[c];
        const int peos = POS_EOS[c], ppad = POS_PAD[c];
        for (int slot = t; slot < M_OUT; slot += TPB) {
            int vc, vp;
            if (slot < cnt) {
                const int p = s_packed[base + slot];
                vc = p & 0xFFF;
                vp = p >> 12;
            } else if (slot == cnt) {
                vc = CONTENT_EOS;
                vp = peos;
            } else {
                vc = CONTENT_PAD;
                vp = ppad;
            }
            dst_c[slot] = vc;
            dst_p[slot] = vp;
            dst_s[slot] = c;
        }
    }
}

extern "C" void kernel_launch(void* const* d_in, const int* in_sizes, int n_in,
                              void* d_out, int out_size, void* d_ws, size_t ws_size,
                              hipStream_t stream) {
    const int* indices = (const int*)d_in[0];
    const int* grain   = (const int*)d_in[1];
    int* out = (int*)d_out;

    const int batch = in_sizes[0] / N_TOK;  // 512
    triple_grain_permute<<<batch, TPB, 0, stream>>>(indices, grain, out, batch);
}

// Round 3
// 90.925 us; speedup vs baseline: 1.0220x; 1.0008x over previous
//
#include <hip/hip_runtime.h>

// TripleGrainSeparatePermuter: per-row stable 3-way stream compaction.
// B=512 rows, N=4096 elements/row. 9 outputs of [B, N+1]=[512,4097] int32,
// concatenated flat in d_out in reference return order:
//   0: coarse_content  1: medium_content  2: fine_content
//   3: coarse_position 4: medium_position 5: fine_position
//   6: coarse_segment  7: medium_segment  8: fine_segment

constexpr int N_TOK  = 4096;
constexpr int M_OUT  = N_TOK + 1;   // 4097
constexpr int TPB    = 1024;        // 16 waves/block, 2 blocks/CU -> 32 waves/CU
constexpr int NWAVES = TPB / 64;
constexpr int EPT    = N_TOK / TPB; // 4 elements per thread (contiguous chunk)

constexpr int CONTENT_PAD = 1024, CONTENT_EOS = 1025;
// per-class position pad/eos: coarse 128/129, medium 256/257, fine 1024/1025
__device__ __constant__ int POS_PAD[3] = {128, 256, 1024};
__device__ __constant__ int POS_EOS[3] = {129, 257, 1025};

__global__ __launch_bounds__(TPB, 8) void
triple_grain_permute(const int* __restrict__ indices,
                     const int* __restrict__ grain,
                     int* __restrict__ out,
                     int batch) {
    const int b = blockIdx.x;
    const int t = threadIdx.x;
    const int lane = t & 63;
    const int wave = t >> 6;

    const int* idx_row = indices + (size_t)b * N_TOK;
    const int* g_row   = grain   + (size_t)b * N_TOK;

    // packed per-token word: content (bits 0..11, values<=1023) | pos<<12 (<=4095)
    __shared__ int s_packed[N_TOK];
    __shared__ unsigned int s_wave_tot[NWAVES];

    // ---- load my contiguous 4-element chunk (int4, 16B-aligned) ----
    int4 gg = reinterpret_cast<const int4*>(g_row)[t];
    int4 ii = reinterpret_cast<const int4*>(idx_row)[t];
    int gv[EPT] = {gg.x, gg.y, gg.z, gg.w};
    const int elem0 = t * EPT;
    int pv[EPT] = {ii.x | (elem0 << 12),
                   ii.y | ((elem0 + 1) << 12),
                   ii.z | ((elem0 + 2) << 12),
                   ii.w | ((elem0 + 3) << 12)};

    // ---- per-thread class counts (<=4), packed into 10-bit fields.
    // Wave-inclusive field max = 64*4 = 256 < 1024: no cross-field carry in u32.
    int c0 = 0, c1 = 0, c2 = 0;
#pragma unroll
    for (int j = 0; j < EPT; ++j) {
        c0 += (gv[j] == 0);
        c1 += (gv[j] == 1);
        c2 += (gv[j] == 2);
    }
    unsigned int packed = (unsigned)c0 | ((unsigned)c1 << 10) | ((unsigned)c2 << 20);

    // ---- wave-64 inclusive scan, 32-bit (covers all 3 classes at once) ----
    unsigned int inc = packed;
#pragma unroll
    for (int off = 1; off < 64; off <<= 1) {
        unsigned int nb = (unsigned int)__shfl_up((int)inc, off, 64);
        if (lane >= off) inc += nb;
    }
    if (lane == 63) s_wave_tot[wave] = inc;
    __syncthreads();

    // ---- cross-wave combine (per-class, 32-bit fields widened here) ----
    int wp0 = 0, wp1 = 0, wp2 = 0, tot0 = 0, tot1 = 0, tot2 = 0;
#pragma unroll
    for (int w = 0; w < NWAVES; ++w) {
        const unsigned int v = s_wave_tot[w];
        const int f0 = v & 1023, f1 = (v >> 10) & 1023, f2 = (v >> 20) & 1023;
        if (w < wave) { wp0 += f0; wp1 += f1; wp2 += f2; }
        tot0 += f0; tot1 += f1; tot2 += f2;
    }
    const unsigned int exv = inc - packed;   // per-field exclusive (no borrow)
    const int o0 = wp0 + (int)(exv & 1023);
    const int o1 = wp1 + (int)((exv >> 10) & 1023);
    const int o2 = wp2 + (int)((exv >> 20) & 1023);
    const int cnt0 = tot0, cnt1 = tot1, cnt2 = tot2;

    // compacted class segments laid back-to-back in LDS
    const int base0 = 0, base1 = cnt0, base2 = cnt0 + cnt1;

    // ---- scatter my chunk into LDS (stable: contiguous chunk, ordered scan) ----
    int d0 = base0 + o0, d1 = base1 + o1, d2 = base2 + o2;
#pragma unroll
    for (int j = 0; j < EPT; ++j) {
        const int c = gv[j];
        const int dst = (c == 0) ? d0 : ((c == 1) ? d1 : d2);
        s_packed[dst] = pv[j];
        d0 += (c == 0);
        d1 += (c == 1);
        d2 += (c == 2);
    }
    __syncthreads();

    // ---- vectorized coalesced write-out ----
    // Row start (in dwords) = (arr*512 + b)*4097 ≡ b (mod 4), so peeling
    // (4 - (b&3)) & 3 leading slots makes the body exactly int4 (16B) aligned
    // for ALL 9 arrays simultaneously. 1024 threads cover all chunks in one shot.
    const size_t ARR = (size_t)batch * M_OUT;   // elements per output array
    const int peel = (4 - (b & 3)) & 3;
    const int nch  = (M_OUT - peel) >> 2;       // int4 chunks (<= 1024)
    const int rem  = (M_OUT - peel) & 3;        // tail scalars

    const int bases[3] = {base0, base1, base2};
    const int cnts[3]  = {cnt0, cnt1, cnt2};

#pragma unroll
    for (int c = 0; c < 3; ++c) {
        int* dst_c = out + (size_t)c       * ARR + (size_t)b * M_OUT;
        int* dst_p = out + (size_t)(3 + c) * ARR + (size_t)b * M_OUT;
        int* dst_s = out + (size_t)(6 + c) * ARR + (size_t)b * M_OUT;
        const int cnt = cnts[c];
        const int base = bases[c];
        const int peos = POS_EOS[c], ppad = POS_PAD[c];

        auto elem = [&](int slot, int& vc, int& vp) {
            int a = base + slot;
            a = (a > N_TOK - 1) ? (N_TOK - 1) : a;   // clamp: pad lanes read junk, discarded
            const int pk = s_packed[a];
            vc = (slot < cnt) ? (pk & 0xFFF) : ((slot == cnt) ? CONTENT_EOS : CONTENT_PAD);
            vp = (slot < cnt) ? (pk >> 12)   : ((slot == cnt) ? peos : ppad);
        };

        if (t < peel) {                      // leading scalars to alignment
            int vc, vp;
            elem(t, vc, vp);
            dst_c[t] = vc; dst_p[t] = vp; dst_s[t] = c;
        }
        if (t < nch) {                       // aligned int4 body, one chunk/thread
            const int s0 = peel + 4 * t;
            int4 vc4, vp4;
            elem(s0 + 0, vc4.x, vp4.x);
            elem(s0 + 1, vc4.y, vp4.y);
            elem(s0 + 2, vc4.z, vp4.z);
            elem(s0 + 3, vc4.w, vp4.w);
            *reinterpret_cast<int4*>(dst_c + s0) = vc4;
            *reinterpret_cast<int4*>(dst_p + s0) = vp4;
            *reinterpret_cast<int4*>(dst_s + s0) = make_int4(c, c, c, c);
        }
        if (t < rem) {                       // tail scalars
            const int slot = M_OUT - rem + t;
            int vc, vp;
            elem(slot, vc, vp);
            dst_c[slot] = vc; dst_p[slot] = vp; dst_s[slot] = c;
        }
    }
}

extern "C" void kernel_launch(void* const* d_in, const int* in_sizes, int n_in,
                              void* d_out, int out_size, void* d_ws, size_t ws_size,
                              hipStream_t stream) {
    const int* indices = (const int*)d_in[0];
    const int* grain   = (const int*)d_in[1];
    int* out = (int*)d_out;

    const int batch = in_sizes[0] / N_TOK;  // 512
    triple_grain_permute<<<batch, TPB, 0, stream>>>(indices, grain, out, batch);
}